// Round 2
// baseline (210.154 us; speedup 1.0000x reference)
//
#include <hip/hip_runtime.h>

#define BB 32
#define NN 1024
#define CC 192
#define HH 3
#define DD 64
#define BHND 6291456   // B*H*N*D == B*N*C

typedef __bf16 bf16x8 __attribute__((ext_vector_type(8)));
typedef float  f32x4  __attribute__((ext_vector_type(4)));

// Static device scratch.
__device__ __align__(16) unsigned short g_q  [BHND];        // (b,h,n,d) bf16, pre-scaled by mult(b,h)
__device__ __align__(16) unsigned short g_k  [BHND];        // (b,h,n,d) bf16
__device__ __align__(16) unsigned short g_vt [BHND];        // (b,h,d,n) bf16 (V transposed)
__device__ __align__(16) unsigned short g_ao [BHND];        // (b,n,c) bf16 pre-projection attn out
__device__ __align__(16) unsigned short g_wb [3 * CC * CC]; // qkv_w bf16 (576x192)
__device__ __align__(16) unsigned short g_pwb[CC * CC];     // proj_w bf16 (192x192)
__device__ float g_conf[BB];

__device__ __forceinline__ unsigned short f2b(float f) {  // RNE fp32->bf16
    union { float f; unsigned int i; } z; z.f = f;
    return (unsigned short)((z.i + 0x7fffu + ((z.i >> 16) & 1u)) >> 16);
}

// ---------------- Weight convert (fp32 -> bf16) + conf zero ----------------
__global__ __launch_bounds__(256) void convert_kernel(
    const float* __restrict__ qw, const float* __restrict__ pw)
{
    const int i = blockIdx.x * 256 + threadIdx.x;   // float4 index
    if (blockIdx.x == 0 && threadIdx.x < BB) g_conf[threadIdx.x] = 0.0f;
    float4 v; unsigned short* dst;
    if (i < 27648) { v = ((const float4*)qw)[i];         dst = g_wb  + i * 4; }
    else           { v = ((const float4*)pw)[i - 27648]; dst = g_pwb + (i - 27648) * 4; }
    const unsigned int a = (unsigned int)f2b(v.x) | ((unsigned int)f2b(v.y) << 16);
    const unsigned int b = (unsigned int)f2b(v.z) | ((unsigned int)f2b(v.w) << 16);
    *(uint2*)dst = make_uint2(a, b);
}

// ---------------- QKV projection: MFMA, row-split 4x + wave column-halves --
// grid = 1024 blocks x 256 threads; block covers 32 rows.
// Wave wv: strip = wv>>1 (rows), half = wv&1 (columns: half0 = Q + V[0:96],
// half1 = K + V[96:192]). No redundant HBM traffic: halves sharing a strip
// read the same X rows -> L1 hit. 4 blocks/CU = 4 waves/SIMD (was 1/SIMD).
__global__ __launch_bounds__(256, 4) void qkv_kernel(
    const float* __restrict__ x,
    const float* __restrict__ bias,
    const float* __restrict__ tp,
    const float* __restrict__ ta)
{
    const int tid   = threadIdx.x;
    const int wv    = tid >> 6;
    const int lane  = tid & 63;
    const int q     = lane >> 4;
    const int mq    = lane & 15;
    const int strip = wv >> 1;
    const int half  = wv & 1;
    const int base  = blockIdx.x * 32;
    const int r0    = base + strip * 16;
    const int b     = base >> 10;
    const int nloc  = (base & 1023) + strip * 16;   // n within batch

    // A fragments (fp32 -> bf16), one 16-row strip
    bf16x8 af[6];
    #pragma unroll
    for (int kh = 0; kh < 6; ++kh) {
        const int row = r0 + mq;
        const float4 u0 = *(const float4*)(x + (size_t)row * CC + kh * 32 + q * 8);
        const float4 u1 = *(const float4*)(x + (size_t)row * CC + kh * 32 + q * 8 + 4);
        union { bf16x8 v; unsigned short s_[8]; } t;
        t.s_[0] = f2b(u0.x); t.s_[1] = f2b(u0.y); t.s_[2] = f2b(u0.z); t.s_[3] = f2b(u0.w);
        t.s_[4] = f2b(u1.x); t.s_[5] = f2b(u1.y); t.s_[6] = f2b(u1.z); t.s_[7] = f2b(u1.w);
        af[kh] = t.v;
    }

    // per-head multiplier (Q part only; K uses 1.0 -> f2b identical)
    float mult_h[HH];
    if (half == 0) {
        #pragma unroll
        for (int h = 0; h < HH; ++h) {
            const float tau_e = (0.1f + logf(1.0f + __expf(tp[h]))) * 1.5f; // anneal = 1.5
            mult_h[h] = 0.125f / (ta[b * 3 + h] + tau_e);
        }
    } else {
        mult_h[0] = mult_h[1] = mult_h[2] = 1.0f;
    }

    // ---- Q (half 0) or K (half 1): 12 col-tiles, reg double-buffered B ----
    const int wofs = half * 192;
    unsigned short* const dst = half ? g_k : g_q;
    bf16x8 bcur[6];
    #pragma unroll
    for (int kh = 0; kh < 6; ++kh)
        bcur[kh] = *(const bf16x8*)(g_wb + (size_t)(wofs + mq) * CC + kh * 32 + q * 8);
    #pragma unroll 2
    for (int ot = 0; ot < 12; ++ot) {
        const int col = ot * 16;
        bf16x8 bnxt[6];
        if (ot < 11) {
            #pragma unroll
            for (int kh = 0; kh < 6; ++kh)
                bnxt[kh] = *(const bf16x8*)(g_wb + (size_t)(wofs + col + 16 + mq) * CC + kh * 32 + q * 8);
        }
        f32x4 acc = (f32x4){0.f,0.f,0.f,0.f};
        #pragma unroll
        for (int kh = 0; kh < 6; ++kh)
            acc = __builtin_amdgcn_mfma_f32_16x16x32_bf16(af[kh], bcur[kh], acc, 0, 0, 0);
        const float bv = bias[wofs + col + mq];
        const int h = col >> 6, d0 = col & 63;
        const float m = mult_h[h];
        unsigned short* dp = dst + ((size_t)((b * 3 + h) * NN + nloc + q * 4)) * DD + d0 + mq;
        #pragma unroll
        for (int r = 0; r < 4; ++r)
            dp[(size_t)r * DD] = f2b((acc[r] + bv) * m);
        #pragma unroll
        for (int kh = 0; kh < 6; ++kh) bcur[kh] = bnxt[kh];
    }

    // ---- V col-tiles (6 per wave): swapped operands -> transposed output ---
    const int vofs = 384 + half * 96;
    #pragma unroll
    for (int kh = 0; kh < 6; ++kh)
        bcur[kh] = *(const bf16x8*)(g_wb + (size_t)(vofs + mq) * CC + kh * 32 + q * 8);
    #pragma unroll 2
    for (int ot = 0; ot < 6; ++ot) {
        const int dd0 = half * 96 + ot * 16;
        bf16x8 bnxt[6];
        if (ot < 5) {
            #pragma unroll
            for (int kh = 0; kh < 6; ++kh)
                bnxt[kh] = *(const bf16x8*)(g_wb + (size_t)(vofs + ot * 16 + 16 + mq) * CC + kh * 32 + q * 8);
        }
        f32x4 acc = (f32x4){0.f,0.f,0.f,0.f};
        #pragma unroll
        for (int kh = 0; kh < 6; ++kh)
            acc = __builtin_amdgcn_mfma_f32_16x16x32_bf16(bcur[kh], af[kh], acc, 0, 0, 0);
        #pragma unroll
        for (int r = 0; r < 4; ++r) {
            const int dd = dd0 + q * 4 + r;
            const int h = dd >> 6, d = dd & 63;
            const float bv = bias[384 + dd];
            g_vt[((size_t)((b * 3 + h) * DD + d)) * NN + nloc + mq] = f2b(acc[r] + bv);
        }
        #pragma unroll
        for (int kh = 0; kh < 6; ++kh) bcur[kh] = bnxt[kh];
    }
}

// ---------------- Attention: MFMA flash, 128 queries/block, dbuf K/V -------
// grid = B*H*(N/128) = 768 blocks, 256 threads. Wave wv owns q-strips
// n0+wv*16 (s=0) and n0+64+wv*16 (s=1); every staged fragment feeds 2 MFMAs.
__global__ __launch_bounds__(256, 3) void attn_kernel(
    const float* __restrict__ dl)
{
    const int tid  = threadIdx.x;
    const int wv   = tid >> 6;
    const int lane = tid & 63;
    const int q    = lane >> 4;
    const int mq   = lane & 15;

    const int bh = blockIdx.x >> 3;        // 8 q-tiles of 128 per (b,h)
    const int n0 = (blockIdx.x & 7) * 128;
    const int b  = bh / 3;
    const int h  = bh - b * 3;
    const float keep = 1.0f - 0.3f / (1.0f + __expf(-dl[h]));

    __shared__ __align__(16) unsigned short ks[2][4096];  // 16 KB
    __shared__ __align__(16) unsigned short vt[2][4096];  // 16 KB
    __shared__ __align__(16) unsigned short pt[8192];     // 16 KB (2 strips)
    __shared__ float conf_s[128];

    // Q fragments for both strips (direct global loads)
    const size_t qra = (size_t)(bh * NN + n0 + wv * 16 + mq) * DD;
    const size_t qrb = qra + (size_t)64 * DD;
    const bf16x8 qfa0 = *(const bf16x8*)(g_q + qra + q * 8);
    const bf16x8 qfa1 = *(const bf16x8*)(g_q + qra + 32 + q * 8);
    const bf16x8 qfb0 = *(const bf16x8*)(g_q + qrb + q * 8);
    const bf16x8 qfb1 = *(const bf16x8*)(g_q + qrb + 32 + q * 8);

    // prefetch K/V tile 0
    const size_t krow0 = (size_t)(bh * NN + wv * 16 + mq) * DD;
    const size_t vrow  = (size_t)(bh * DD + wv * 16 + mq) * NN;
    bf16x8 kr0 = *(const bf16x8*)(g_k + krow0 + q * 8);
    bf16x8 kr1 = *(const bf16x8*)(g_k + krow0 + 32 + q * 8);
    bf16x8 vr0 = *(const bf16x8*)(g_vt + vrow + q * 8);
    bf16x8 vr1 = *(const bf16x8*)(g_vt + vrow + 32 + q * 8);

    f32x4 oa[4], ob[4];
    #pragma unroll
    for (int i = 0; i < 4; ++i) { oa[i] = (f32x4){0.f,0.f,0.f,0.f}; ob[i] = (f32x4){0.f,0.f,0.f,0.f}; }
    float la = 0.0f, lb = 0.0f, pma = 0.0f, pmb = 0.0f;

    for (int it = 0; it < 16; ++it) {
        const int cur = it & 1;
        ((bf16x8*)ks[cur])[tid]       = kr0;
        ((bf16x8*)ks[cur])[256 + tid] = kr1;
        ((bf16x8*)vt[cur])[tid]       = vr0;
        ((bf16x8*)vt[cur])[256 + tid] = vr1;
        if (it < 15) {
            const int t1 = (it + 1) * 64;
            kr0 = *(const bf16x8*)(g_k + krow0 + (size_t)t1 * DD + q * 8);
            kr1 = *(const bf16x8*)(g_k + krow0 + (size_t)t1 * DD + 32 + q * 8);
            vr0 = *(const bf16x8*)(g_vt + vrow + t1 + q * 8);
            vr1 = *(const bf16x8*)(g_vt + vrow + t1 + 32 + q * 8);
        }
        __syncthreads();   // buf[cur] visible; compute(it-2) provably done

        // ---- S^T = K . Q^T for both strips (afr shared) ----
        f32x4 sa[4], sb[4];
        #pragma unroll
        for (int i = 0; i < 4; ++i) { sa[i] = (f32x4){0.f,0.f,0.f,0.f}; sb[i] = (f32x4){0.f,0.f,0.f,0.f}; }
        #pragma unroll
        for (int kh = 0; kh < 2; ++kh) {
            const bf16x8 qfa = kh ? qfa1 : qfa0;
            const bf16x8 qfb = kh ? qfb1 : qfb0;
            #pragma unroll
            for (int kt = 0; kt < 4; ++kt) {
                const bf16x8 afr = ((const bf16x8*)ks[cur])[kh * 256 + kt * 64 + lane];
                sa[kt] = __builtin_amdgcn_mfma_f32_16x16x32_bf16(afr, qfa, sa[kt], 0, 0, 0);
                sb[kt] = __builtin_amdgcn_mfma_f32_16x16x32_bf16(afr, qfb, sb[kt], 0, 0, 0);
            }
        }

        // ---- p = exp(s); per-lane max/sum; pack into per-strip P tiles ----
        #pragma unroll
        for (int s = 0; s < 2; ++s) {
            unsigned short* ptb = pt + s * 4096;
            #pragma unroll
            for (int kt = 0; kt < 4; ++kt) {
                const f32x4 sv = s ? sb[kt] : sa[kt];
                const float p0 = __expf(sv[0]);
                const float p1 = __expf(sv[1]);
                const float p2 = __expf(sv[2]);
                const float p3 = __expf(sv[3]);
                const float mx = fmaxf(fmaxf(p0, p1), fmaxf(p2, p3));
                if (s) { pmb = fmaxf(pmb, mx); lb += (p0 + p1) + (p2 + p3); }
                else   { pma = fmaxf(pma, mx); la += (p0 + p1) + (p2 + p3); }
                const unsigned int ua = (__float_as_uint(p0) >> 16) | (__float_as_uint(p1) & 0xffff0000u);
                const unsigned int ub = (__float_as_uint(p2) >> 16) | (__float_as_uint(p3) & 0xffff0000u);
                const int kh2   = kt >> 1;
                const int qk    = (kt * 2 + (q >> 1)) & 3;
                const int chunk = ((wv * 2 + kh2) * 4 + qk) * 16 + mq;
                *(uint2*)((char*)ptb + chunk * 16 + (q & 1) * 8) = make_uint2(ua, ub);
            }
        }
        __builtin_amdgcn_s_waitcnt(0xC07F);   // lgkmcnt(0): own-wave pt visibility

        // ---- O += P V for both strips (vf shared) ----
        #pragma unroll
        for (int kh = 0; kh < 2; ++kh) {
            const bf16x8 pfa = ((const bf16x8*)pt)[(wv * 2 + kh) * 64 + lane];
            const bf16x8 pfb = ((const bf16x8*)(pt + 4096))[(wv * 2 + kh) * 64 + lane];
            #pragma unroll
            for (int ctv = 0; ctv < 4; ++ctv) {
                const bf16x8 vf = ((const bf16x8*)vt[cur])[kh * 256 + ctv * 64 + lane];
                oa[ctv] = __builtin_amdgcn_mfma_f32_16x16x32_bf16(pfa, vf, oa[ctv], 0, 0, 0);
                ob[ctv] = __builtin_amdgcn_mfma_f32_16x16x32_bf16(pfb, vf, ob[ctv], 0, 0, 0);
            }
        }
    }

    // ---- reductions over quads (lane owns query row mq of each strip) ----
    float l0 = la, l1 = lb;
    l0 += __shfl_xor(l0, 16, 64); l0 += __shfl_xor(l0, 32, 64);
    l1 += __shfl_xor(l1, 16, 64); l1 += __shfl_xor(l1, 32, 64);
    float p0 = pma, p1 = pmb;
    p0 = fmaxf(p0, __shfl_xor(p0, 16, 64)); p0 = fmaxf(p0, __shfl_xor(p0, 32, 64));
    p1 = fmaxf(p1, __shfl_xor(p1, 16, 64)); p1 = fmaxf(p1, __shfl_xor(p1, 32, 64));
    const float invla = 1.0f / l0;
    const float invlb = 1.0f / l1;

    if (lane < 16) {
        conf_s[wv * 16 + mq]      = p0 * invla;
        conf_s[64 + wv * 16 + mq] = p1 * invlb;
    }
    __syncthreads();
    if (tid < 64) {
        float v = conf_s[tid] + conf_s[64 + tid];
        #pragma unroll
        for (int off = 1; off <= 32; off <<= 1) v += __shfl_xor(v, off, 64);
        if (tid == 0) atomicAdd(&g_conf[b], v);
    }

    // ---- epilogue per strip ----
    #pragma unroll
    for (int s = 0; s < 2; ++s) {
        const float invl = s ? invlb : invla;
        float sc[4];
        #pragma unroll
        for (int r = 0; r < 4; ++r)
            sc[r] = keep * __int_as_float(
                __builtin_amdgcn_ds_bpermute((q * 4 + r) << 2, __float_as_int(invl)));
        #pragma unroll
        for (int ctv = 0; ctv < 4; ++ctv)
            #pragma unroll
            for (int r = 0; r < 4; ++r) {
                const f32x4 o = s ? ob[ctv] : oa[ctv];
                g_ao[((size_t)(b * NN + n0 + s * 64 + wv * 16 + q * 4 + r)) * CC + h * DD + ctv * 16 + mq] =
                    f2b(o[r] * sc[r]);
            }
    }
}

// ---------------- Projection + residual + conf finalize: row-split 4x ------
// grid = 1024 blocks of 32 rows; wave = (strip, column-half). 4 blocks/CU.
__global__ __launch_bounds__(256, 4) void proj_kernel(
    const float* __restrict__ pb,
    const float* __restrict__ rp,
    const float* __restrict__ x,
    float* __restrict__ out,
    float* __restrict__ out_c)
{
    const int tid   = threadIdx.x;
    const int wv    = tid >> 6;
    const int lane  = tid & 63;
    const int q     = lane >> 4;
    const int mq    = lane & 15;
    const int strip = wv >> 1;
    const int half  = wv & 1;
    const int base  = blockIdx.x * 32;
    const int r0    = base + strip * 16;

    if (blockIdx.x == 0 && tid < BB)
        out_c[tid] = g_conf[tid] * (1.0f / (float)(HH * NN));   // attn complete

    const float wres = 1.0f / (1.0f + __expf(-rp[0]));

    bf16x8 af[6];
    #pragma unroll
    for (int kh = 0; kh < 6; ++kh)
        af[kh] = *(const bf16x8*)(g_ao + (size_t)(r0 + mq) * CC + kh * 32 + q * 8);

    const int wofs = half * 96;
    bf16x8 bcur[6];
    #pragma unroll
    for (int kh = 0; kh < 6; ++kh)
        bcur[kh] = *(const bf16x8*)(g_pwb + (size_t)(wofs + mq) * CC + kh * 32 + q * 8);
    #pragma unroll 2
    for (int ot = 0; ot < 6; ++ot) {
        const int o0 = wofs + ot * 16;
        bf16x8 bnxt[6];
        if (ot < 5) {
            #pragma unroll
            for (int kh = 0; kh < 6; ++kh)
                bnxt[kh] = *(const bf16x8*)(g_pwb + (size_t)(o0 + 16 + mq) * CC + kh * 32 + q * 8);
        }
        f32x4 acc = (f32x4){0.f,0.f,0.f,0.f};
        #pragma unroll
        for (int kh = 0; kh < 6; ++kh)
            acc = __builtin_amdgcn_mfma_f32_16x16x32_bf16(af[kh], bcur[kh], acc, 0, 0, 0);
        const float bv = pb[o0 + mq];
        #pragma unroll
        for (int r = 0; r < 4; ++r) {
            const int n = r0 + q * 4 + r;
            const float xv = x[(size_t)n * CC + o0 + mq];
            out[(size_t)n * CC + o0 + mq] = wres * (acc[r] + bv) + (1.0f - wres) * xv;
        }
        #pragma unroll
        for (int kh = 0; kh < 6; ++kh) bcur[kh] = bnxt[kh];
    }
}

extern "C" void kernel_launch(void* const* d_in, const int* in_sizes, int n_in,
                              void* d_out, int out_size, void* d_ws, size_t ws_size,
                              hipStream_t stream)
{
    const float* x  = (const float*)d_in[0];
    const float* qw = (const float*)d_in[1];
    const float* qb = (const float*)d_in[2];
    const float* pw = (const float*)d_in[3];
    const float* pb = (const float*)d_in[4];
    const float* tp = (const float*)d_in[5];
    const float* dl = (const float*)d_in[6];
    const float* rp = (const float*)d_in[7];
    const float* ta = (const float*)d_in[8];

    float* out   = (float*)d_out;
    float* out_c = out + (size_t)BB * NN * CC;

    convert_kernel<<<144, 256, 0, stream>>>(qw, pw);
    qkv_kernel<<<(BB * NN) / 32, 256, 0, stream>>>(x, qb, tp, ta);
    attn_kernel<<<BB * HH * (NN / 128), 256, 0, stream>>>(dl);
    proj_kernel<<<(BB * NN) / 32, 256, 0, stream>>>(pb, rp, x, out, out_c);
}

// Round 3
// 166.665 us; speedup vs baseline: 1.2609x; 1.2609x over previous
//
#include <hip/hip_runtime.h>

#define BB 32
#define NN 1024
#define CC 192
#define HH 3
#define DD 64
#define BHND 6291456   // B*H*N*D == B*N*C

typedef __bf16 bf16x8 __attribute__((ext_vector_type(8)));
typedef float  f32x4  __attribute__((ext_vector_type(4)));

// Static device scratch.
__device__ __align__(16) unsigned short g_q  [BHND];        // (b,h,n,d) bf16, pre-scaled by mult(b,h)
__device__ __align__(16) unsigned short g_k  [BHND];        // (b,h,n,d) bf16
__device__ __align__(16) unsigned short g_vt [BHND];        // (b,h,d,n) bf16 (V transposed)
__device__ __align__(16) unsigned short g_ao [BHND];        // (b,n,c) bf16 pre-projection attn out
// Weights stored PRE-PACKED in MFMA fragment order:
//   element for (tile, kh, lane, j) at ((tile*6+kh)*64 + lane)*8 + j
//   value = W[col = tile*16 + (lane&15)][k = kh*32 + (lane>>4)*8 + j]
__device__ __align__(16) unsigned short g_wb [3 * CC * CC]; // qkv_w packed (36 tiles)
__device__ __align__(16) unsigned short g_pwb[CC * CC];     // proj_w packed (12 tiles)
__device__ float g_conf[BB];

__device__ __forceinline__ unsigned short f2b(float f) {  // RNE fp32->bf16
    union { float f; unsigned int i; } z; z.f = f;
    return (unsigned short)((z.i + 0x7fffu + ((z.i >> 16) & 1u)) >> 16);
}

// ---------------- Weight convert + PACK (fp32 -> bf16 fragment order) ------
// grid = 144 x 256 = 36864 threads; thread owns one uint2 (4 bf16) of packed.
__global__ __launch_bounds__(256) void convert_kernel(
    const float* __restrict__ qw, const float* __restrict__ pw)
{
    const int u = blockIdx.x * 256 + threadIdx.x;
    if (blockIdx.x == 0 && threadIdx.x < BB) g_conf[threadIdx.x] = 0.0f;
    const float* src; unsigned short* dstb; int p;
    if (u < 27648) { src = qw; dstb = g_wb;  p = u; }          // 36*6*64*2
    else           { src = pw; dstb = g_pwb; p = u - 27648; }  // 12*6*64*2
    const int jh   = p & 1;
    const int lane = (p >> 1) & 63;
    const int fg   = p >> 7;           // tile*6 + kh
    const int kh   = fg % 6;
    const int t    = fg / 6;
    const int mq   = lane & 15;
    const int q    = lane >> 4;
    const int col  = t * 16 + mq;
    const int k    = kh * 32 + q * 8 + jh * 4;
    const float4 v = *(const float4*)(src + (size_t)col * CC + k);
    const unsigned int a = (unsigned int)f2b(v.x) | ((unsigned int)f2b(v.y) << 16);
    const unsigned int b = (unsigned int)f2b(v.z) | ((unsigned int)f2b(v.w) << 16);
    *(uint2*)(dstb + (size_t)p * 4) = make_uint2(a, b);
}

// ---------------- QKV projection: coalesced B (packed) + LDS-staged A ------
// grid = 1024 blocks x 256 threads; block covers 32 rows.
// Wave wv: strip = wv>>1 (16 rows), half = wv&1 (half0 = Q + V[0:96],
// half1 = K + V[96:192]). All fragment loads are contiguous (no TA gathers).
__global__ __launch_bounds__(256, 4) void qkv_kernel(
    const float* __restrict__ x,
    const float* __restrict__ bias,
    const float* __restrict__ tp,
    const float* __restrict__ ta)
{
    const int tid   = threadIdx.x;
    const int wv    = tid >> 6;
    const int lane  = tid & 63;
    const int q     = lane >> 4;
    const int mq    = lane & 15;
    const int strip = wv >> 1;
    const int half  = wv & 1;
    const int base  = blockIdx.x * 32;
    const int b     = base >> 10;
    const int nloc  = (base & 1023) + strip * 16;   // n within batch

    // ---- stage X slab (32 rows x 192 fp32, contiguous) -> LDS bf16 [32][200]
    __shared__ __align__(16) unsigned short xa[32 * 200];   // 12.8 KB
    const float* xb = x + (size_t)base * CC;
    #pragma unroll
    for (int c = 0; c < 6; ++c) {
        const int f   = c * 256 + tid;          // float4 idx, 1536 total
        const float4 u = *(const float4*)(xb + (size_t)f * 4);
        const int row = f / 48;
        const int kk  = (f - row * 48) * 4;
        const unsigned int a  = (unsigned int)f2b(u.x) | ((unsigned int)f2b(u.y) << 16);
        const unsigned int b2 = (unsigned int)f2b(u.z) | ((unsigned int)f2b(u.w) << 16);
        *(uint2*)(&xa[row * 200 + kk]) = make_uint2(a, b2);
    }
    __syncthreads();

    // A fragments from LDS (row stride 400B: 16B-aligned, bank-spread)
    bf16x8 af[6];
    #pragma unroll
    for (int kh = 0; kh < 6; ++kh)
        af[kh] = *(const bf16x8*)(&xa[(strip * 16 + mq) * 200 + kh * 32 + q * 8]);

    // per-head multiplier (Q part only; K uses 1.0 -> bits identical)
    float mult_h[HH];
    if (half == 0) {
        #pragma unroll
        for (int h = 0; h < HH; ++h) {
            const float tau_e = (0.1f + logf(1.0f + __expf(tp[h]))) * 1.5f; // anneal = 1.5
            mult_h[h] = 0.125f / (ta[b * 3 + h] + tau_e);
        }
    } else {
        mult_h[0] = mult_h[1] = mult_h[2] = 1.0f;
    }

    // ---- Q (half 0) or K (half 1): 12 col-tiles, packed-coalesced B stream -
    const int tbase = half * 12;                 // Q tiles 0..11, K 12..23
    unsigned short* const dst = half ? g_k : g_q;
    bf16x8 bcur[6];
    #pragma unroll
    for (int kh = 0; kh < 6; ++kh)
        bcur[kh] = *(const bf16x8*)(g_wb + ((size_t)(tbase * 6 + kh) * 64 + lane) * 8);
    #pragma unroll 2
    for (int ot = 0; ot < 12; ++ot) {
        bf16x8 bnxt[6];
        if (ot < 11) {
            #pragma unroll
            for (int kh = 0; kh < 6; ++kh)
                bnxt[kh] = *(const bf16x8*)(g_wb + ((size_t)((tbase + ot + 1) * 6 + kh) * 64 + lane) * 8);
        }
        f32x4 acc = (f32x4){0.f,0.f,0.f,0.f};
        #pragma unroll
        for (int kh = 0; kh < 6; ++kh)
            acc = __builtin_amdgcn_mfma_f32_16x16x32_bf16(af[kh], bcur[kh], acc, 0, 0, 0);
        const int col = ot * 16;
        const float bv = bias[half * 192 + col + mq];
        const int h = col >> 6, d0 = col & 63;
        const float m = mult_h[h];
        unsigned short* dp = dst + ((size_t)((b * 3 + h) * NN + nloc + q * 4)) * DD + d0 + mq;
        #pragma unroll
        for (int r = 0; r < 4; ++r)
            dp[(size_t)r * DD] = f2b((acc[r] + bv) * m);
        #pragma unroll
        for (int kh = 0; kh < 6; ++kh) bcur[kh] = bnxt[kh];
    }

    // ---- V col-tiles (6 per wave): swapped operands -> transposed output ---
    const int vbase = 24 + half * 6;
    #pragma unroll
    for (int kh = 0; kh < 6; ++kh)
        bcur[kh] = *(const bf16x8*)(g_wb + ((size_t)(vbase * 6 + kh) * 64 + lane) * 8);
    #pragma unroll 2
    for (int ot = 0; ot < 6; ++ot) {
        const int dd0 = half * 96 + ot * 16;
        bf16x8 bnxt[6];
        if (ot < 5) {
            #pragma unroll
            for (int kh = 0; kh < 6; ++kh)
                bnxt[kh] = *(const bf16x8*)(g_wb + ((size_t)((vbase + ot + 1) * 6 + kh) * 64 + lane) * 8);
        }
        f32x4 acc = (f32x4){0.f,0.f,0.f,0.f};
        #pragma unroll
        for (int kh = 0; kh < 6; ++kh)
            acc = __builtin_amdgcn_mfma_f32_16x16x32_bf16(bcur[kh], af[kh], acc, 0, 0, 0);
        #pragma unroll
        for (int r = 0; r < 4; ++r) {
            const int dd = dd0 + q * 4 + r;
            const int h = dd >> 6, d = dd & 63;
            const float bv = bias[384 + dd];
            g_vt[((size_t)((b * 3 + h) * DD + d)) * NN + nloc + mq] = f2b(acc[r] + bv);
        }
        #pragma unroll
        for (int kh = 0; kh < 6; ++kh) bcur[kh] = bnxt[kh];
    }
}

// ---------------- Attention: MFMA flash, 128 queries/block, dbuf K/V -------
// grid = B*H*(N/128) = 768 blocks, 256 threads. Wave wv owns q-strips
// n0+wv*16 (s=0) and n0+64+wv*16 (s=1); every staged fragment feeds 2 MFMAs.
__global__ __launch_bounds__(256, 3) void attn_kernel(
    const float* __restrict__ dl)
{
    const int tid  = threadIdx.x;
    const int wv   = tid >> 6;
    const int lane = tid & 63;
    const int q    = lane >> 4;
    const int mq   = lane & 15;

    const int bh = blockIdx.x >> 3;        // 8 q-tiles of 128 per (b,h)
    const int n0 = (blockIdx.x & 7) * 128;
    const int b  = bh / 3;
    const int h  = bh - b * 3;
    const float keep = 1.0f - 0.3f / (1.0f + __expf(-dl[h]));

    __shared__ __align__(16) unsigned short ks[2][4096];  // 16 KB
    __shared__ __align__(16) unsigned short vt[2][4096];  // 16 KB
    __shared__ __align__(16) unsigned short pt[8192];     // 16 KB (2 strips)
    __shared__ float conf_s[128];

    // Q fragments for both strips (direct global loads)
    const size_t qra = (size_t)(bh * NN + n0 + wv * 16 + mq) * DD;
    const size_t qrb = qra + (size_t)64 * DD;
    const bf16x8 qfa0 = *(const bf16x8*)(g_q + qra + q * 8);
    const bf16x8 qfa1 = *(const bf16x8*)(g_q + qra + 32 + q * 8);
    const bf16x8 qfb0 = *(const bf16x8*)(g_q + qrb + q * 8);
    const bf16x8 qfb1 = *(const bf16x8*)(g_q + qrb + 32 + q * 8);

    // prefetch K/V tile 0
    const size_t krow0 = (size_t)(bh * NN + wv * 16 + mq) * DD;
    const size_t vrow  = (size_t)(bh * DD + wv * 16 + mq) * NN;
    bf16x8 kr0 = *(const bf16x8*)(g_k + krow0 + q * 8);
    bf16x8 kr1 = *(const bf16x8*)(g_k + krow0 + 32 + q * 8);
    bf16x8 vr0 = *(const bf16x8*)(g_vt + vrow + q * 8);
    bf16x8 vr1 = *(const bf16x8*)(g_vt + vrow + 32 + q * 8);

    f32x4 oa[4], ob[4];
    #pragma unroll
    for (int i = 0; i < 4; ++i) { oa[i] = (f32x4){0.f,0.f,0.f,0.f}; ob[i] = (f32x4){0.f,0.f,0.f,0.f}; }
    float la = 0.0f, lb = 0.0f, pma = 0.0f, pmb = 0.0f;

    for (int it = 0; it < 16; ++it) {
        const int cur = it & 1;
        ((bf16x8*)ks[cur])[tid]       = kr0;
        ((bf16x8*)ks[cur])[256 + tid] = kr1;
        ((bf16x8*)vt[cur])[tid]       = vr0;
        ((bf16x8*)vt[cur])[256 + tid] = vr1;
        if (it < 15) {
            const int t1 = (it + 1) * 64;
            kr0 = *(const bf16x8*)(g_k + krow0 + (size_t)t1 * DD + q * 8);
            kr1 = *(const bf16x8*)(g_k + krow0 + (size_t)t1 * DD + 32 + q * 8);
            vr0 = *(const bf16x8*)(g_vt + vrow + t1 + q * 8);
            vr1 = *(const bf16x8*)(g_vt + vrow + t1 + 32 + q * 8);
        }
        __syncthreads();   // buf[cur] visible; compute(it-2) provably done

        // ---- S^T = K . Q^T for both strips (afr shared) ----
        f32x4 sa[4], sb[4];
        #pragma unroll
        for (int i = 0; i < 4; ++i) { sa[i] = (f32x4){0.f,0.f,0.f,0.f}; sb[i] = (f32x4){0.f,0.f,0.f,0.f}; }
        #pragma unroll
        for (int kh = 0; kh < 2; ++kh) {
            const bf16x8 qfa = kh ? qfa1 : qfa0;
            const bf16x8 qfb = kh ? qfb1 : qfb0;
            #pragma unroll
            for (int kt = 0; kt < 4; ++kt) {
                const bf16x8 afr = ((const bf16x8*)ks[cur])[kh * 256 + kt * 64 + lane];
                sa[kt] = __builtin_amdgcn_mfma_f32_16x16x32_bf16(afr, qfa, sa[kt], 0, 0, 0);
                sb[kt] = __builtin_amdgcn_mfma_f32_16x16x32_bf16(afr, qfb, sb[kt], 0, 0, 0);
            }
        }

        // ---- p = exp(s); per-lane max/sum; pack into per-strip P tiles ----
        #pragma unroll
        for (int s = 0; s < 2; ++s) {
            unsigned short* ptb = pt + s * 4096;
            #pragma unroll
            for (int kt = 0; kt < 4; ++kt) {
                const f32x4 sv = s ? sb[kt] : sa[kt];
                const float p0 = __expf(sv[0]);
                const float p1 = __expf(sv[1]);
                const float p2 = __expf(sv[2]);
                const float p3 = __expf(sv[3]);
                const float mx = fmaxf(fmaxf(p0, p1), fmaxf(p2, p3));
                if (s) { pmb = fmaxf(pmb, mx); lb += (p0 + p1) + (p2 + p3); }
                else   { pma = fmaxf(pma, mx); la += (p0 + p1) + (p2 + p3); }
                const unsigned int ua = (__float_as_uint(p0) >> 16) | (__float_as_uint(p1) & 0xffff0000u);
                const unsigned int ub = (__float_as_uint(p2) >> 16) | (__float_as_uint(p3) & 0xffff0000u);
                const int kh2   = kt >> 1;
                const int qk    = (kt * 2 + (q >> 1)) & 3;
                const int chunk = ((wv * 2 + kh2) * 4 + qk) * 16 + mq;
                *(uint2*)((char*)ptb + chunk * 16 + (q & 1) * 8) = make_uint2(ua, ub);
            }
        }
        __builtin_amdgcn_s_waitcnt(0xC07F);   // lgkmcnt(0): own-wave pt visibility

        // ---- O += P V for both strips (vf shared) ----
        #pragma unroll
        for (int kh = 0; kh < 2; ++kh) {
            const bf16x8 pfa = ((const bf16x8*)pt)[(wv * 2 + kh) * 64 + lane];
            const bf16x8 pfb = ((const bf16x8*)(pt + 4096))[(wv * 2 + kh) * 64 + lane];
            #pragma unroll
            for (int ctv = 0; ctv < 4; ++ctv) {
                const bf16x8 vf = ((const bf16x8*)vt[cur])[kh * 256 + ctv * 64 + lane];
                oa[ctv] = __builtin_amdgcn_mfma_f32_16x16x32_bf16(pfa, vf, oa[ctv], 0, 0, 0);
                ob[ctv] = __builtin_amdgcn_mfma_f32_16x16x32_bf16(pfb, vf, ob[ctv], 0, 0, 0);
            }
        }
    }

    // ---- reductions over quads (lane owns query row mq of each strip) ----
    float l0 = la, l1 = lb;
    l0 += __shfl_xor(l0, 16, 64); l0 += __shfl_xor(l0, 32, 64);
    l1 += __shfl_xor(l1, 16, 64); l1 += __shfl_xor(l1, 32, 64);
    float p0 = pma, p1 = pmb;
    p0 = fmaxf(p0, __shfl_xor(p0, 16, 64)); p0 = fmaxf(p0, __shfl_xor(p0, 32, 64));
    p1 = fmaxf(p1, __shfl_xor(p1, 16, 64)); p1 = fmaxf(p1, __shfl_xor(p1, 32, 64));
    const float invla = 1.0f / l0;
    const float invlb = 1.0f / l1;

    if (lane < 16) {
        conf_s[wv * 16 + mq]      = p0 * invla;
        conf_s[64 + wv * 16 + mq] = p1 * invlb;
    }
    __syncthreads();
    if (tid < 64) {
        float v = conf_s[tid] + conf_s[64 + tid];
        #pragma unroll
        for (int off = 1; off <= 32; off <<= 1) v += __shfl_xor(v, off, 64);
        if (tid == 0) atomicAdd(&g_conf[b], v);
    }

    // ---- epilogue per strip ----
    #pragma unroll
    for (int s = 0; s < 2; ++s) {
        const float invl = s ? invlb : invla;
        float sc[4];
        #pragma unroll
        for (int r = 0; r < 4; ++r)
            sc[r] = keep * __int_as_float(
                __builtin_amdgcn_ds_bpermute((q * 4 + r) << 2, __float_as_int(invl)));
        #pragma unroll
        for (int ctv = 0; ctv < 4; ++ctv)
            #pragma unroll
            for (int r = 0; r < 4; ++r) {
                const f32x4 o = s ? ob[ctv] : oa[ctv];
                g_ao[((size_t)(b * NN + n0 + s * 64 + wv * 16 + q * 4 + r)) * CC + h * DD + ctv * 16 + mq] =
                    f2b(o[r] * sc[r]);
            }
    }
}

// ---------------- Projection: coalesced B (packed) + LDS-staged A ----------
// grid = 1024 blocks of 32 rows; wave = (strip, column-half). 4 blocks/CU.
__global__ __launch_bounds__(256, 4) void proj_kernel(
    const float* __restrict__ pb,
    const float* __restrict__ rp,
    const float* __restrict__ x,
    float* __restrict__ out,
    float* __restrict__ out_c)
{
    const int tid   = threadIdx.x;
    const int wv    = tid >> 6;
    const int lane  = tid & 63;
    const int q     = lane >> 4;
    const int mq    = lane & 15;
    const int strip = wv >> 1;
    const int half  = wv & 1;
    const int base  = blockIdx.x * 32;
    const int r0    = base + strip * 16;

    if (blockIdx.x == 0 && tid < BB)
        out_c[tid] = g_conf[tid] * (1.0f / (float)(HH * NN));   // attn complete

    const float wres = 1.0f / (1.0f + __expf(-rp[0]));

    // ---- stage g_ao slab (32 rows x 192 bf16, contiguous) -> LDS [32][200]
    __shared__ __align__(16) unsigned short xa[32 * 200];   // 12.8 KB
    const unsigned short* aob = g_ao + (size_t)base * CC;
    #pragma unroll
    for (int c = 0; c < 3; ++c) {
        const int f   = c * 256 + tid;          // 16B-unit idx, 768 total
        const int row = f / 24;
        const int k8  = (f - row * 24) * 8;
        *(bf16x8*)(&xa[row * 200 + k8]) = *(const bf16x8*)(aob + (size_t)f * 8);
    }
    __syncthreads();

    bf16x8 af[6];
    #pragma unroll
    for (int kh = 0; kh < 6; ++kh)
        af[kh] = *(const bf16x8*)(&xa[(strip * 16 + mq) * 200 + kh * 32 + q * 8]);

    const int tbase = half * 6;
    bf16x8 bcur[6];
    #pragma unroll
    for (int kh = 0; kh < 6; ++kh)
        bcur[kh] = *(const bf16x8*)(g_pwb + ((size_t)(tbase * 6 + kh) * 64 + lane) * 8);
    #pragma unroll 2
    for (int ot = 0; ot < 6; ++ot) {
        const int o0 = half * 96 + ot * 16;
        bf16x8 bnxt[6];
        if (ot < 5) {
            #pragma unroll
            for (int kh = 0; kh < 6; ++kh)
                bnxt[kh] = *(const bf16x8*)(g_pwb + ((size_t)((tbase + ot + 1) * 6 + kh) * 64 + lane) * 8);
        }
        f32x4 acc = (f32x4){0.f,0.f,0.f,0.f};
        #pragma unroll
        for (int kh = 0; kh < 6; ++kh)
            acc = __builtin_amdgcn_mfma_f32_16x16x32_bf16(af[kh], bcur[kh], acc, 0, 0, 0);
        const float bv = pb[o0 + mq];
        #pragma unroll
        for (int r = 0; r < 4; ++r) {
            const int n = r0 + q * 4 + r;
            const float xv = x[(size_t)n * CC + o0 + mq];
            out[(size_t)n * CC + o0 + mq] = wres * (acc[r] + bv) + (1.0f - wres) * xv;
        }
        #pragma unroll
        for (int kh = 0; kh < 6; ++kh) bcur[kh] = bnxt[kh];
    }
}

extern "C" void kernel_launch(void* const* d_in, const int* in_sizes, int n_in,
                              void* d_out, int out_size, void* d_ws, size_t ws_size,
                              hipStream_t stream)
{
    const float* x  = (const float*)d_in[0];
    const float* qw = (const float*)d_in[1];
    const float* qb = (const float*)d_in[2];
    const float* pw = (const float*)d_in[3];
    const float* pb = (const float*)d_in[4];
    const float* tp = (const float*)d_in[5];
    const float* dl = (const float*)d_in[6];
    const float* rp = (const float*)d_in[7];
    const float* ta = (const float*)d_in[8];

    float* out   = (float*)d_out;
    float* out_c = out + (size_t)BB * NN * CC;

    convert_kernel<<<144, 256, 0, stream>>>(qw, pw);
    qkv_kernel<<<(BB * NN) / 32, 256, 0, stream>>>(x, qb, tp, ta);
    attn_kernel<<<BB * HH * (NN / 128), 256, 0, stream>>>(dl);
    proj_kernel<<<(BB * NN) / 32, 256, 0, stream>>>(pb, rp, x, out, out_c);
}

// Round 4
// 162.023 us; speedup vs baseline: 1.2971x; 1.0286x over previous
//
#include <hip/hip_runtime.h>

#define BB 32
#define NN 1024
#define CC 192
#define HH 3
#define DD 64
#define BHND 6291456   // B*H*N*D == B*N*C

typedef __bf16 bf16x8 __attribute__((ext_vector_type(8)));
typedef float  f32x4  __attribute__((ext_vector_type(4)));

// Static device scratch.
__device__ __align__(16) unsigned short g_q  [BHND];        // (b,h,n,d) bf16, pre-scaled by mult(b,h)
__device__ __align__(16) unsigned short g_k  [BHND];        // (b,h,n,d) bf16
__device__ __align__(16) unsigned short g_vt [BHND];        // (b,h,d,n) bf16 (V transposed)
__device__ __align__(16) unsigned short g_ao [BHND];        // (b,n,c) bf16 pre-projection attn out
// Weights stored PRE-PACKED in MFMA fragment order:
//   element for (tile, kh, lane, j) at ((tile*6+kh)*64 + lane)*8 + j
//   value = W[col = tile*16 + (lane&15)][k = kh*32 + (lane>>4)*8 + j]
__device__ __align__(16) unsigned short g_wb [3 * CC * CC]; // qkv_w packed (36 tiles)
__device__ __align__(16) unsigned short g_pwb[CC * CC];     // proj_w packed (12 tiles)
__device__ float g_conf[BB];

__device__ __forceinline__ unsigned short f2b(float f) {  // RNE fp32->bf16
    union { float f; unsigned int i; } z; z.f = f;
    return (unsigned short)((z.i + 0x7fffu + ((z.i >> 16) & 1u)) >> 16);
}

// ---------------- Weight convert + PACK (fp32 -> bf16 fragment order) ------
// grid = 144 x 256 = 36864 threads; thread owns one uint2 (4 bf16) of packed.
__global__ __launch_bounds__(256) void convert_kernel(
    const float* __restrict__ qw, const float* __restrict__ pw)
{
    const int u = blockIdx.x * 256 + threadIdx.x;
    if (blockIdx.x == 0 && threadIdx.x < BB) g_conf[threadIdx.x] = 0.0f;
    const float* src; unsigned short* dstb; int p;
    if (u < 27648) { src = qw; dstb = g_wb;  p = u; }          // 36*6*64*2
    else           { src = pw; dstb = g_pwb; p = u - 27648; }  // 12*6*64*2
    const int jh   = p & 1;
    const int lane = (p >> 1) & 63;
    const int fg   = p >> 7;           // tile*6 + kh
    const int kh   = fg % 6;
    const int t    = fg / 6;
    const int mq   = lane & 15;
    const int q    = lane >> 4;
    const int col  = t * 16 + mq;
    const int k    = kh * 32 + q * 8 + jh * 4;
    const float4 v = *(const float4*)(src + (size_t)col * CC + k);
    const unsigned int a = (unsigned int)f2b(v.x) | ((unsigned int)f2b(v.y) << 16);
    const unsigned int b = (unsigned int)f2b(v.z) | ((unsigned int)f2b(v.w) << 16);
    *(uint2*)(dstb + (size_t)p * 4) = make_uint2(a, b);
}

// ---------------- QKV projection: coalesced B (packed) + LDS-staged A ------
// grid = 1024 blocks x 256 threads; block covers 32 rows.
// Wave wv: strip = wv>>1 (16 rows), half = wv&1 (half0 = Q + V[0:96],
// half1 = K + V[96:192]). All fragment loads are contiguous (no TA gathers).
__global__ __launch_bounds__(256, 4) void qkv_kernel(
    const float* __restrict__ x,
    const float* __restrict__ bias,
    const float* __restrict__ tp,
    const float* __restrict__ ta)
{
    const int tid   = threadIdx.x;
    const int wv    = tid >> 6;
    const int lane  = tid & 63;
    const int q     = lane >> 4;
    const int mq    = lane & 15;
    const int strip = wv >> 1;
    const int half  = wv & 1;
    const int base  = blockIdx.x * 32;
    const int b     = base >> 10;
    const int nloc  = (base & 1023) + strip * 16;   // n within batch

    // ---- stage X slab (32 rows x 192 fp32, contiguous) -> LDS bf16 [32][200]
    __shared__ __align__(16) unsigned short xa[32 * 200];   // 12.8 KB
    const float* xb = x + (size_t)base * CC;
    #pragma unroll
    for (int c = 0; c < 6; ++c) {
        const int f   = c * 256 + tid;          // float4 idx, 1536 total
        const float4 u = *(const float4*)(xb + (size_t)f * 4);
        const int row = f / 48;
        const int kk  = (f - row * 48) * 4;
        const unsigned int a  = (unsigned int)f2b(u.x) | ((unsigned int)f2b(u.y) << 16);
        const unsigned int b2 = (unsigned int)f2b(u.z) | ((unsigned int)f2b(u.w) << 16);
        *(uint2*)(&xa[row * 200 + kk]) = make_uint2(a, b2);
    }
    __syncthreads();

    // A fragments from LDS (row stride 400B: 16B-aligned, bank-spread)
    bf16x8 af[6];
    #pragma unroll
    for (int kh = 0; kh < 6; ++kh)
        af[kh] = *(const bf16x8*)(&xa[(strip * 16 + mq) * 200 + kh * 32 + q * 8]);

    // per-head multiplier (Q part only; K uses 1.0 -> bits identical)
    float mult_h[HH];
    if (half == 0) {
        #pragma unroll
        for (int h = 0; h < HH; ++h) {
            const float tau_e = (0.1f + logf(1.0f + __expf(tp[h]))) * 1.5f; // anneal = 1.5
            mult_h[h] = 0.125f / (ta[b * 3 + h] + tau_e);
        }
    } else {
        mult_h[0] = mult_h[1] = mult_h[2] = 1.0f;
    }

    // ---- Q (half 0) or K (half 1): 12 col-tiles, packed-coalesced B stream -
    const int tbase = half * 12;                 // Q tiles 0..11, K 12..23
    unsigned short* const dst = half ? g_k : g_q;
    bf16x8 bcur[6];
    #pragma unroll
    for (int kh = 0; kh < 6; ++kh)
        bcur[kh] = *(const bf16x8*)(g_wb + ((size_t)(tbase * 6 + kh) * 64 + lane) * 8);
    #pragma unroll 2
    for (int ot = 0; ot < 12; ++ot) {
        bf16x8 bnxt[6];
        if (ot < 11) {
            #pragma unroll
            for (int kh = 0; kh < 6; ++kh)
                bnxt[kh] = *(const bf16x8*)(g_wb + ((size_t)((tbase + ot + 1) * 6 + kh) * 64 + lane) * 8);
        }
        f32x4 acc = (f32x4){0.f,0.f,0.f,0.f};
        #pragma unroll
        for (int kh = 0; kh < 6; ++kh)
            acc = __builtin_amdgcn_mfma_f32_16x16x32_bf16(af[kh], bcur[kh], acc, 0, 0, 0);
        const int col = ot * 16;
        const float bv = bias[half * 192 + col + mq];
        const int h = col >> 6, d0 = col & 63;
        const float m = mult_h[h];
        unsigned short* dp = dst + ((size_t)((b * 3 + h) * NN + nloc + q * 4)) * DD + d0 + mq;
        #pragma unroll
        for (int r = 0; r < 4; ++r)
            dp[(size_t)r * DD] = f2b((acc[r] + bv) * m);
        #pragma unroll
        for (int kh = 0; kh < 6; ++kh) bcur[kh] = bnxt[kh];
    }

    // ---- V col-tiles (6 per wave): swapped operands -> transposed output ---
    const int vbase = 24 + half * 6;
    #pragma unroll
    for (int kh = 0; kh < 6; ++kh)
        bcur[kh] = *(const bf16x8*)(g_wb + ((size_t)(vbase * 6 + kh) * 64 + lane) * 8);
    #pragma unroll 2
    for (int ot = 0; ot < 6; ++ot) {
        const int dd0 = half * 96 + ot * 16;
        bf16x8 bnxt[6];
        if (ot < 5) {
            #pragma unroll
            for (int kh = 0; kh < 6; ++kh)
                bnxt[kh] = *(const bf16x8*)(g_wb + ((size_t)((vbase + ot + 1) * 6 + kh) * 64 + lane) * 8);
        }
        f32x4 acc = (f32x4){0.f,0.f,0.f,0.f};
        #pragma unroll
        for (int kh = 0; kh < 6; ++kh)
            acc = __builtin_amdgcn_mfma_f32_16x16x32_bf16(bcur[kh], af[kh], acc, 0, 0, 0);
        #pragma unroll
        for (int r = 0; r < 4; ++r) {
            const int dd = dd0 + q * 4 + r;
            const int h = dd >> 6, d = dd & 63;
            const float bv = bias[384 + dd];
            g_vt[((size_t)((b * 3 + h) * DD + d)) * NN + nloc + mq] = f2b(acc[r] + bv);
        }
        #pragma unroll
        for (int kh = 0; kh < 6; ++kh) bcur[kh] = bnxt[kh];
    }
}

// ---------------- Attention: MFMA flash, 128 queries/block, dbuf K/V -------
// grid = 768 blocks, 256 threads. XCD-aware remap: dispatch round-robins
// blockIdx%8 across the 8 XCDs, so give each XCD 12 (b,h) pairs with ALL 8
// of their q-tiles (12 x 256KB K/V = 3MB < 4MB L2/XCD). All 96 blocks of an
// XCD are co-resident (3 blocks/CU x 32 CU), so K/V is HBM-fetched once per
// XCD instead of 8x: FETCH 108MB -> ~36MB.
__global__ __launch_bounds__(256, 3) void attn_kernel(
    const float* __restrict__ dl)
{
    const int tid  = threadIdx.x;
    const int wv   = tid >> 6;
    const int lane = tid & 63;
    const int q    = lane >> 4;
    const int mq   = lane & 15;

    const int xcd = blockIdx.x & 7;
    const int ii  = blockIdx.x >> 3;       // 0..95
    const int bh  = xcd * 12 + (ii >> 3);  // 12 bh per XCD, all q-tiles local
    const int n0  = (ii & 7) * 128;
    const int b  = bh / 3;
    const int h  = bh - b * 3;
    const float keep = 1.0f - 0.3f / (1.0f + __expf(-dl[h]));

    __shared__ __align__(16) unsigned short ks[2][4096];  // 16 KB
    __shared__ __align__(16) unsigned short vt[2][4096];  // 16 KB
    __shared__ __align__(16) unsigned short pt[8192];     // 16 KB (2 strips)
    __shared__ float conf_s[128];

    // Q fragments for both strips (direct global loads)
    const size_t qra = (size_t)(bh * NN + n0 + wv * 16 + mq) * DD;
    const size_t qrb = qra + (size_t)64 * DD;
    const bf16x8 qfa0 = *(const bf16x8*)(g_q + qra + q * 8);
    const bf16x8 qfa1 = *(const bf16x8*)(g_q + qra + 32 + q * 8);
    const bf16x8 qfb0 = *(const bf16x8*)(g_q + qrb + q * 8);
    const bf16x8 qfb1 = *(const bf16x8*)(g_q + qrb + 32 + q * 8);

    // prefetch K/V tile 0
    const size_t krow0 = (size_t)(bh * NN + wv * 16 + mq) * DD;
    const size_t vrow  = (size_t)(bh * DD + wv * 16 + mq) * NN;
    bf16x8 kr0 = *(const bf16x8*)(g_k + krow0 + q * 8);
    bf16x8 kr1 = *(const bf16x8*)(g_k + krow0 + 32 + q * 8);
    bf16x8 vr0 = *(const bf16x8*)(g_vt + vrow + q * 8);
    bf16x8 vr1 = *(const bf16x8*)(g_vt + vrow + 32 + q * 8);

    f32x4 oa[4], ob[4];
    #pragma unroll
    for (int i = 0; i < 4; ++i) { oa[i] = (f32x4){0.f,0.f,0.f,0.f}; ob[i] = (f32x4){0.f,0.f,0.f,0.f}; }
    float la = 0.0f, lb = 0.0f, pma = 0.0f, pmb = 0.0f;

    for (int it = 0; it < 16; ++it) {
        const int cur = it & 1;
        ((bf16x8*)ks[cur])[tid]       = kr0;
        ((bf16x8*)ks[cur])[256 + tid] = kr1;
        ((bf16x8*)vt[cur])[tid]       = vr0;
        ((bf16x8*)vt[cur])[256 + tid] = vr1;
        if (it < 15) {
            const int t1 = (it + 1) * 64;
            kr0 = *(const bf16x8*)(g_k + krow0 + (size_t)t1 * DD + q * 8);
            kr1 = *(const bf16x8*)(g_k + krow0 + (size_t)t1 * DD + 32 + q * 8);
            vr0 = *(const bf16x8*)(g_vt + vrow + t1 + q * 8);
            vr1 = *(const bf16x8*)(g_vt + vrow + t1 + 32 + q * 8);
        }
        __syncthreads();   // buf[cur] visible; compute(it-2) provably done

        // ---- S^T = K . Q^T for both strips (afr shared) ----
        f32x4 sa[4], sb[4];
        #pragma unroll
        for (int i = 0; i < 4; ++i) { sa[i] = (f32x4){0.f,0.f,0.f,0.f}; sb[i] = (f32x4){0.f,0.f,0.f,0.f}; }
        #pragma unroll
        for (int kh = 0; kh < 2; ++kh) {
            const bf16x8 qfa = kh ? qfa1 : qfa0;
            const bf16x8 qfb = kh ? qfb1 : qfb0;
            #pragma unroll
            for (int kt = 0; kt < 4; ++kt) {
                const bf16x8 afr = ((const bf16x8*)ks[cur])[kh * 256 + kt * 64 + lane];
                sa[kt] = __builtin_amdgcn_mfma_f32_16x16x32_bf16(afr, qfa, sa[kt], 0, 0, 0);
                sb[kt] = __builtin_amdgcn_mfma_f32_16x16x32_bf16(afr, qfb, sb[kt], 0, 0, 0);
            }
        }

        // ---- p = exp(s); per-lane max/sum; pack into per-strip P tiles ----
        #pragma unroll
        for (int s = 0; s < 2; ++s) {
            unsigned short* ptb = pt + s * 4096;
            #pragma unroll
            for (int kt = 0; kt < 4; ++kt) {
                const f32x4 sv = s ? sb[kt] : sa[kt];
                const float p0 = __expf(sv[0]);
                const float p1 = __expf(sv[1]);
                const float p2 = __expf(sv[2]);
                const float p3 = __expf(sv[3]);
                const float mx = fmaxf(fmaxf(p0, p1), fmaxf(p2, p3));
                if (s) { pmb = fmaxf(pmb, mx); lb += (p0 + p1) + (p2 + p3); }
                else   { pma = fmaxf(pma, mx); la += (p0 + p1) + (p2 + p3); }
                const unsigned int ua = (__float_as_uint(p0) >> 16) | (__float_as_uint(p1) & 0xffff0000u);
                const unsigned int ub = (__float_as_uint(p2) >> 16) | (__float_as_uint(p3) & 0xffff0000u);
                const int kh2   = kt >> 1;
                const int qk    = (kt * 2 + (q >> 1)) & 3;
                const int chunk = ((wv * 2 + kh2) * 4 + qk) * 16 + mq;
                *(uint2*)((char*)ptb + chunk * 16 + (q & 1) * 8) = make_uint2(ua, ub);
            }
        }
        __builtin_amdgcn_s_waitcnt(0xC07F);   // lgkmcnt(0): own-wave pt visibility

        // ---- O += P V for both strips (vf shared) ----
        #pragma unroll
        for (int kh = 0; kh < 2; ++kh) {
            const bf16x8 pfa = ((const bf16x8*)pt)[(wv * 2 + kh) * 64 + lane];
            const bf16x8 pfb = ((const bf16x8*)(pt + 4096))[(wv * 2 + kh) * 64 + lane];
            #pragma unroll
            for (int ctv = 0; ctv < 4; ++ctv) {
                const bf16x8 vf = ((const bf16x8*)vt[cur])[kh * 256 + ctv * 64 + lane];
                oa[ctv] = __builtin_amdgcn_mfma_f32_16x16x32_bf16(pfa, vf, oa[ctv], 0, 0, 0);
                ob[ctv] = __builtin_amdgcn_mfma_f32_16x16x32_bf16(pfb, vf, ob[ctv], 0, 0, 0);
            }
        }
    }

    // ---- reductions over quads (lane owns query row mq of each strip) ----
    float l0 = la, l1 = lb;
    l0 += __shfl_xor(l0, 16, 64); l0 += __shfl_xor(l0, 32, 64);
    l1 += __shfl_xor(l1, 16, 64); l1 += __shfl_xor(l1, 32, 64);
    float p0 = pma, p1 = pmb;
    p0 = fmaxf(p0, __shfl_xor(p0, 16, 64)); p0 = fmaxf(p0, __shfl_xor(p0, 32, 64));
    p1 = fmaxf(p1, __shfl_xor(p1, 16, 64)); p1 = fmaxf(p1, __shfl_xor(p1, 32, 64));
    const float invla = 1.0f / l0;
    const float invlb = 1.0f / l1;

    if (lane < 16) {
        conf_s[wv * 16 + mq]      = p0 * invla;
        conf_s[64 + wv * 16 + mq] = p1 * invlb;
    }
    __syncthreads();
    if (tid < 64) {
        float v = conf_s[tid] + conf_s[64 + tid];
        #pragma unroll
        for (int off = 1; off <= 32; off <<= 1) v += __shfl_xor(v, off, 64);
        if (tid == 0) atomicAdd(&g_conf[b], v);
    }

    // ---- epilogue per strip ----
    #pragma unroll
    for (int s = 0; s < 2; ++s) {
        const float invl = s ? invlb : invla;
        float sc[4];
        #pragma unroll
        for (int r = 0; r < 4; ++r)
            sc[r] = keep * __int_as_float(
                __builtin_amdgcn_ds_bpermute((q * 4 + r) << 2, __float_as_int(invl)));
        #pragma unroll
        for (int ctv = 0; ctv < 4; ++ctv)
            #pragma unroll
            for (int r = 0; r < 4; ++r) {
                const f32x4 o = s ? ob[ctv] : oa[ctv];
                g_ao[((size_t)(b * NN + n0 + s * 64 + wv * 16 + q * 4 + r)) * CC + h * DD + ctv * 16 + mq] =
                    f2b(o[r] * sc[r]);
            }
    }
}

// ---------------- Projection: coalesced B (packed) + LDS-staged A ----------
// grid = 1024 blocks of 32 rows; wave = (strip, column-half). 4 blocks/CU.
__global__ __launch_bounds__(256, 4) void proj_kernel(
    const float* __restrict__ pb,
    const float* __restrict__ rp,
    const float* __restrict__ x,
    float* __restrict__ out,
    float* __restrict__ out_c)
{
    const int tid   = threadIdx.x;
    const int wv    = tid >> 6;
    const int lane  = tid & 63;
    const int q     = lane >> 4;
    const int mq    = lane & 15;
    const int strip = wv >> 1;
    const int half  = wv & 1;
    const int base  = blockIdx.x * 32;
    const int r0    = base + strip * 16;

    if (blockIdx.x == 0 && tid < BB)
        out_c[tid] = g_conf[tid] * (1.0f / (float)(HH * NN));   // attn complete

    const float wres = 1.0f / (1.0f + __expf(-rp[0]));

    // ---- stage g_ao slab (32 rows x 192 bf16, contiguous) -> LDS [32][200]
    __shared__ __align__(16) unsigned short xa[32 * 200];   // 12.8 KB
    const unsigned short* aob = g_ao + (size_t)base * CC;
    #pragma unroll
    for (int c = 0; c < 3; ++c) {
        const int f   = c * 256 + tid;          // 16B-unit idx, 768 total
        const int row = f / 24;
        const int k8  = (f - row * 24) * 8;
        *(bf16x8*)(&xa[row * 200 + k8]) = *(const bf16x8*)(aob + (size_t)f * 8);
    }
    __syncthreads();

    bf16x8 af[6];
    #pragma unroll
    for (int kh = 0; kh < 6; ++kh)
        af[kh] = *(const bf16x8*)(&xa[(strip * 16 + mq) * 200 + kh * 32 + q * 8]);

    const int tbase = half * 6;
    bf16x8 bcur[6];
    #pragma unroll
    for (int kh = 0; kh < 6; ++kh)
        bcur[kh] = *(const bf16x8*)(g_pwb + ((size_t)(tbase * 6 + kh) * 64 + lane) * 8);
    #pragma unroll 2
    for (int ot = 0; ot < 6; ++ot) {
        const int o0 = half * 96 + ot * 16;
        bf16x8 bnxt[6];
        if (ot < 5) {
            #pragma unroll
            for (int kh = 0; kh < 6; ++kh)
                bnxt[kh] = *(const bf16x8*)(g_pwb + ((size_t)((tbase + ot + 1) * 6 + kh) * 64 + lane) * 8);
        }
        f32x4 acc = (f32x4){0.f,0.f,0.f,0.f};
        #pragma unroll
        for (int kh = 0; kh < 6; ++kh)
            acc = __builtin_amdgcn_mfma_f32_16x16x32_bf16(af[kh], bcur[kh], acc, 0, 0, 0);
        const float bv = pb[o0 + mq];
        #pragma unroll
        for (int r = 0; r < 4; ++r) {
            const int n = r0 + q * 4 + r;
            const float xv = x[(size_t)n * CC + o0 + mq];
            out[(size_t)n * CC + o0 + mq] = wres * (acc[r] + bv) + (1.0f - wres) * xv;
        }
        #pragma unroll
        for (int kh = 0; kh < 6; ++kh) bcur[kh] = bnxt[kh];
    }
}

extern "C" void kernel_launch(void* const* d_in, const int* in_sizes, int n_in,
                              void* d_out, int out_size, void* d_ws, size_t ws_size,
                              hipStream_t stream)
{
    const float* x  = (const float*)d_in[0];
    const float* qw = (const float*)d_in[1];
    const float* qb = (const float*)d_in[2];
    const float* pw = (const float*)d_in[3];
    const float* pb = (const float*)d_in[4];
    const float* tp = (const float*)d_in[5];
    const float* dl = (const float*)d_in[6];
    const float* rp = (const float*)d_in[7];
    const float* ta = (const float*)d_in[8];

    float* out   = (float*)d_out;
    float* out_c = out + (size_t)BB * NN * CC;

    convert_kernel<<<144, 256, 0, stream>>>(qw, pw);
    qkv_kernel<<<(BB * NN) / 32, 256, 0, stream>>>(x, qb, tp, ta);
    attn_kernel<<<BB * HH * (NN / 128), 256, 0, stream>>>(dl);
    proj_kernel<<<(BB * NN) / 32, 256, 0, stream>>>(pb, rp, x, out, out_c);
}

// Round 5
// 160.153 us; speedup vs baseline: 1.3122x; 1.0117x over previous
//
#include <hip/hip_runtime.h>

#define BB 32
#define NN 1024
#define CC 192
#define HH 3
#define DD 64
#define BHND 6291456   // B*H*N*D == B*N*C

typedef __bf16 bf16x8 __attribute__((ext_vector_type(8)));
typedef float  f32x4  __attribute__((ext_vector_type(4)));

// Static device scratch.
__device__ __align__(16) unsigned short g_q  [BHND];        // (b,h,n,d) bf16, pre-scaled by mult(b,h)
__device__ __align__(16) unsigned short g_k  [BHND];        // (b,h,n,d) bf16
__device__ __align__(16) unsigned short g_vt [BHND];        // (b,h,d,n) bf16 (V transposed)
__device__ __align__(16) unsigned short g_ao [BHND];        // (b,n,c) bf16 pre-projection attn out
// Weights stored PRE-PACKED in MFMA fragment order:
//   element for (tile, kh, lane, j) at ((tile*6+kh)*64 + lane)*8 + j
//   value = W[col = tile*16 + (lane&15)][k = kh*32 + (lane>>4)*8 + j]
__device__ __align__(16) unsigned short g_wb [3 * CC * CC]; // qkv_w packed (36 tiles)
__device__ __align__(16) unsigned short g_pwb[CC * CC];     // proj_w packed (12 tiles)
__device__ float g_conf[BB];

__device__ __forceinline__ unsigned short f2b(float f) {  // RNE fp32->bf16
    union { float f; unsigned int i; } z; z.f = f;
    return (unsigned short)((z.i + 0x7fffu + ((z.i >> 16) & 1u)) >> 16);
}

// ---------------- Weight convert + PACK (fp32 -> bf16 fragment order) ------
// grid = 144 x 256 = 36864 threads; thread owns one uint2 (4 bf16) of packed.
__global__ __launch_bounds__(256) void convert_kernel(
    const float* __restrict__ qw, const float* __restrict__ pw)
{
    const int u = blockIdx.x * 256 + threadIdx.x;
    if (blockIdx.x == 0 && threadIdx.x < BB) g_conf[threadIdx.x] = 0.0f;
    const float* src; unsigned short* dstb; int p;
    if (u < 27648) { src = qw; dstb = g_wb;  p = u; }          // 36*6*64*2
    else           { src = pw; dstb = g_pwb; p = u - 27648; }  // 12*6*64*2
    const int jh   = p & 1;
    const int lane = (p >> 1) & 63;
    const int fg   = p >> 7;           // tile*6 + kh
    const int kh   = fg % 6;
    const int t    = fg / 6;
    const int mq   = lane & 15;
    const int q    = lane >> 4;
    const int col  = t * 16 + mq;
    const int k    = kh * 32 + q * 8 + jh * 4;
    const float4 v = *(const float4*)(src + (size_t)col * CC + k);
    const unsigned int a = (unsigned int)f2b(v.x) | ((unsigned int)f2b(v.y) << 16);
    const unsigned int b = (unsigned int)f2b(v.z) | ((unsigned int)f2b(v.w) << 16);
    *(uint2*)(dstb + (size_t)p * 4) = make_uint2(a, b);
}

// ---------------- QKV projection: coalesced B (packed) + LDS-staged A ------
// grid = 1024 blocks x 256 threads; block covers 32 rows.
// Wave wv: strip = wv>>1 (16 rows), half = wv&1 (half0 = Q + V[0:96],
// half1 = K + V[96:192]). All fragment loads are contiguous (no TA gathers).
__global__ __launch_bounds__(256, 4) void qkv_kernel(
    const float* __restrict__ x,
    const float* __restrict__ bias,
    const float* __restrict__ tp,
    const float* __restrict__ ta)
{
    const int tid   = threadIdx.x;
    const int wv    = tid >> 6;
    const int lane  = tid & 63;
    const int q     = lane >> 4;
    const int mq    = lane & 15;
    const int strip = wv >> 1;
    const int half  = wv & 1;
    const int base  = blockIdx.x * 32;
    const int b     = base >> 10;
    const int nloc  = (base & 1023) + strip * 16;   // n within batch

    // ---- stage X slab (32 rows x 192 fp32, contiguous) -> LDS bf16 [32][200]
    __shared__ __align__(16) unsigned short xa[32 * 200];   // 12.8 KB
    const float* xb = x + (size_t)base * CC;
    #pragma unroll
    for (int c = 0; c < 6; ++c) {
        const int f   = c * 256 + tid;          // float4 idx, 1536 total
        const float4 u = *(const float4*)(xb + (size_t)f * 4);
        const int row = f / 48;
        const int kk  = (f - row * 48) * 4;
        const unsigned int a  = (unsigned int)f2b(u.x) | ((unsigned int)f2b(u.y) << 16);
        const unsigned int b2 = (unsigned int)f2b(u.z) | ((unsigned int)f2b(u.w) << 16);
        *(uint2*)(&xa[row * 200 + kk]) = make_uint2(a, b2);
    }
    __syncthreads();

    // A fragments from LDS (row stride 400B: 16B-aligned, bank-spread)
    bf16x8 af[6];
    #pragma unroll
    for (int kh = 0; kh < 6; ++kh)
        af[kh] = *(const bf16x8*)(&xa[(strip * 16 + mq) * 200 + kh * 32 + q * 8]);

    // per-head multiplier (Q part only; K uses 1.0 -> bits identical)
    float mult_h[HH];
    if (half == 0) {
        #pragma unroll
        for (int h = 0; h < HH; ++h) {
            const float tau_e = (0.1f + logf(1.0f + __expf(tp[h]))) * 1.5f; // anneal = 1.5
            mult_h[h] = 0.125f / (ta[b * 3 + h] + tau_e);
        }
    } else {
        mult_h[0] = mult_h[1] = mult_h[2] = 1.0f;
    }

    // ---- Q (half 0) or K (half 1): 12 col-tiles, packed-coalesced B stream -
    const int tbase = half * 12;                 // Q tiles 0..11, K 12..23
    unsigned short* const dst = half ? g_k : g_q;
    bf16x8 bcur[6];
    #pragma unroll
    for (int kh = 0; kh < 6; ++kh)
        bcur[kh] = *(const bf16x8*)(g_wb + ((size_t)(tbase * 6 + kh) * 64 + lane) * 8);
    #pragma unroll 2
    for (int ot = 0; ot < 12; ++ot) {
        bf16x8 bnxt[6];
        if (ot < 11) {
            #pragma unroll
            for (int kh = 0; kh < 6; ++kh)
                bnxt[kh] = *(const bf16x8*)(g_wb + ((size_t)((tbase + ot + 1) * 6 + kh) * 64 + lane) * 8);
        }
        f32x4 acc = (f32x4){0.f,0.f,0.f,0.f};
        #pragma unroll
        for (int kh = 0; kh < 6; ++kh)
            acc = __builtin_amdgcn_mfma_f32_16x16x32_bf16(af[kh], bcur[kh], acc, 0, 0, 0);
        const int col = ot * 16;
        const float bv = bias[half * 192 + col + mq];
        const int h = col >> 6, d0 = col & 63;
        const float m = mult_h[h];
        unsigned short* dp = dst + ((size_t)((b * 3 + h) * NN + nloc + q * 4)) * DD + d0 + mq;
        #pragma unroll
        for (int r = 0; r < 4; ++r)
            dp[(size_t)r * DD] = f2b((acc[r] + bv) * m);
        #pragma unroll
        for (int kh = 0; kh < 6; ++kh) bcur[kh] = bnxt[kh];
    }

    // ---- V col-tiles (6 per wave): swapped operands -> transposed output ---
    const int vbase = 24 + half * 6;
    #pragma unroll
    for (int kh = 0; kh < 6; ++kh)
        bcur[kh] = *(const bf16x8*)(g_wb + ((size_t)(vbase * 6 + kh) * 64 + lane) * 8);
    #pragma unroll 2
    for (int ot = 0; ot < 6; ++ot) {
        const int dd0 = half * 96 + ot * 16;
        bf16x8 bnxt[6];
        if (ot < 5) {
            #pragma unroll
            for (int kh = 0; kh < 6; ++kh)
                bnxt[kh] = *(const bf16x8*)(g_wb + ((size_t)((vbase + ot + 1) * 6 + kh) * 64 + lane) * 8);
        }
        f32x4 acc = (f32x4){0.f,0.f,0.f,0.f};
        #pragma unroll
        for (int kh = 0; kh < 6; ++kh)
            acc = __builtin_amdgcn_mfma_f32_16x16x32_bf16(bcur[kh], af[kh], acc, 0, 0, 0);
        #pragma unroll
        for (int r = 0; r < 4; ++r) {
            const int dd = dd0 + q * 4 + r;
            const int h = dd >> 6, d = dd & 63;
            const float bv = bias[384 + dd];
            g_vt[((size_t)((b * 3 + h) * DD + d)) * NN + nloc + mq] = f2b(acc[r] + bv);
        }
        #pragma unroll
        for (int kh = 0; kh < 6; ++kh) bcur[kh] = bnxt[kh];
    }
}

// ---------------- Attention: MFMA flash, 128 queries/block, dbuf K/V -------
// grid = 768 blocks, 256 threads. XCD-aware remap (K/V L2-resident per XCD).
// Key round-5 change: K/V prefetch is issued AFTER __syncthreads, so the
// barrier's implicit s_waitcnt vmcnt(0) finds no outstanding loads (was
// draining the fresh prefetch every iteration = exposed L2 latency for all
// waves simultaneously). Prefetch latency now hides under QK+softmax+PV.
__global__ __launch_bounds__(256, 3) void attn_kernel(
    const float* __restrict__ dl)
{
    const int tid  = threadIdx.x;
    const int wv   = tid >> 6;
    const int lane = tid & 63;
    const int q    = lane >> 4;
    const int mq   = lane & 15;

    const int xcd = blockIdx.x & 7;
    const int ii  = blockIdx.x >> 3;       // 0..95
    const int bh  = xcd * 12 + (ii >> 3);  // 12 bh per XCD, all q-tiles local
    const int n0  = (ii & 7) * 128;
    const int b  = bh / 3;
    const int h  = bh - b * 3;
    const float keep = 1.0f - 0.3f / (1.0f + __expf(-dl[h]));

    __shared__ __align__(16) unsigned short ks[2][4096];  // 16 KB
    __shared__ __align__(16) unsigned short vt[2][4096];  // 16 KB
    __shared__ __align__(16) unsigned short pt[8192];     // 16 KB (2 strips)
    __shared__ float conf_s[128];

    // Q fragments for both strips (direct global loads)
    const size_t qra = (size_t)(bh * NN + n0 + wv * 16 + mq) * DD;
    const size_t qrb = qra + (size_t)64 * DD;
    const bf16x8 qfa0 = *(const bf16x8*)(g_q + qra + q * 8);
    const bf16x8 qfa1 = *(const bf16x8*)(g_q + qra + 32 + q * 8);
    const bf16x8 qfb0 = *(const bf16x8*)(g_q + qrb + q * 8);
    const bf16x8 qfb1 = *(const bf16x8*)(g_q + qrb + 32 + q * 8);

    // prefetch K/V tile 0
    const size_t krow0 = (size_t)(bh * NN + wv * 16 + mq) * DD;
    const size_t vrow  = (size_t)(bh * DD + wv * 16 + mq) * NN;
    bf16x8 kr0 = *(const bf16x8*)(g_k + krow0 + q * 8);
    bf16x8 kr1 = *(const bf16x8*)(g_k + krow0 + 32 + q * 8);
    bf16x8 vr0 = *(const bf16x8*)(g_vt + vrow + q * 8);
    bf16x8 vr1 = *(const bf16x8*)(g_vt + vrow + 32 + q * 8);

    f32x4 oa[4], ob[4];
    #pragma unroll
    for (int i = 0; i < 4; ++i) { oa[i] = (f32x4){0.f,0.f,0.f,0.f}; ob[i] = (f32x4){0.f,0.f,0.f,0.f}; }
    float la = 0.0f, lb = 0.0f, pma = 0.0f, pmb = 0.0f;

    for (int it = 0; it < 16; ++it) {
        const int cur = it & 1;
        ((bf16x8*)ks[cur])[tid]       = kr0;
        ((bf16x8*)ks[cur])[256 + tid] = kr1;
        ((bf16x8*)vt[cur])[tid]       = vr0;
        ((bf16x8*)vt[cur])[256 + tid] = vr1;
        __syncthreads();   // buf[cur] visible; no outstanding VMEM -> cheap

        if (it < 15) {     // prefetch AFTER barrier: latency hides under compute
            const int t1 = (it + 1) * 64;
            kr0 = *(const bf16x8*)(g_k + krow0 + (size_t)t1 * DD + q * 8);
            kr1 = *(const bf16x8*)(g_k + krow0 + (size_t)t1 * DD + 32 + q * 8);
            vr0 = *(const bf16x8*)(g_vt + vrow + t1 + q * 8);
            vr1 = *(const bf16x8*)(g_vt + vrow + t1 + 32 + q * 8);
        }

        // ---- S^T = K . Q^T for both strips (afr shared) ----
        f32x4 sa[4], sb[4];
        #pragma unroll
        for (int i = 0; i < 4; ++i) { sa[i] = (f32x4){0.f,0.f,0.f,0.f}; sb[i] = (f32x4){0.f,0.f,0.f,0.f}; }
        __builtin_amdgcn_s_setprio(1);
        #pragma unroll
        for (int kh = 0; kh < 2; ++kh) {
            const bf16x8 qfa = kh ? qfa1 : qfa0;
            const bf16x8 qfb = kh ? qfb1 : qfb0;
            #pragma unroll
            for (int kt = 0; kt < 4; ++kt) {
                const bf16x8 afr = ((const bf16x8*)ks[cur])[kh * 256 + kt * 64 + lane];
                sa[kt] = __builtin_amdgcn_mfma_f32_16x16x32_bf16(afr, qfa, sa[kt], 0, 0, 0);
                sb[kt] = __builtin_amdgcn_mfma_f32_16x16x32_bf16(afr, qfb, sb[kt], 0, 0, 0);
            }
        }
        __builtin_amdgcn_s_setprio(0);

        // ---- p = exp(s); per-lane max/sum; pack into per-strip P tiles ----
        #pragma unroll
        for (int s = 0; s < 2; ++s) {
            unsigned short* ptb = pt + s * 4096;
            #pragma unroll
            for (int kt = 0; kt < 4; ++kt) {
                const f32x4 sv = s ? sb[kt] : sa[kt];
                const float p0 = __expf(sv[0]);
                const float p1 = __expf(sv[1]);
                const float p2 = __expf(sv[2]);
                const float p3 = __expf(sv[3]);
                const float mx = fmaxf(fmaxf(p0, p1), fmaxf(p2, p3));
                if (s) { pmb = fmaxf(pmb, mx); lb += (p0 + p1) + (p2 + p3); }
                else   { pma = fmaxf(pma, mx); la += (p0 + p1) + (p2 + p3); }
                const unsigned int ua = (__float_as_uint(p0) >> 16) | (__float_as_uint(p1) & 0xffff0000u);
                const unsigned int ub = (__float_as_uint(p2) >> 16) | (__float_as_uint(p3) & 0xffff0000u);
                const int kh2   = kt >> 1;
                const int qk    = (kt * 2 + (q >> 1)) & 3;
                const int chunk = ((wv * 2 + kh2) * 4 + qk) * 16 + mq;
                *(uint2*)((char*)ptb + chunk * 16 + (q & 1) * 8) = make_uint2(ua, ub);
            }
        }
        __builtin_amdgcn_s_waitcnt(0xC07F);   // lgkmcnt(0): own-wave pt visibility

        // ---- O += P V for both strips (vf shared) ----
        __builtin_amdgcn_s_setprio(1);
        #pragma unroll
        for (int kh = 0; kh < 2; ++kh) {
            const bf16x8 pfa = ((const bf16x8*)pt)[(wv * 2 + kh) * 64 + lane];
            const bf16x8 pfb = ((const bf16x8*)(pt + 4096))[(wv * 2 + kh) * 64 + lane];
            #pragma unroll
            for (int ctv = 0; ctv < 4; ++ctv) {
                const bf16x8 vf = ((const bf16x8*)vt[cur])[kh * 256 + ctv * 64 + lane];
                oa[ctv] = __builtin_amdgcn_mfma_f32_16x16x32_bf16(pfa, vf, oa[ctv], 0, 0, 0);
                ob[ctv] = __builtin_amdgcn_mfma_f32_16x16x32_bf16(pfb, vf, ob[ctv], 0, 0, 0);
            }
        }
        __builtin_amdgcn_s_setprio(0);
    }

    // ---- reductions over quads (lane owns query row mq of each strip) ----
    float l0 = la, l1 = lb;
    l0 += __shfl_xor(l0, 16, 64); l0 += __shfl_xor(l0, 32, 64);
    l1 += __shfl_xor(l1, 16, 64); l1 += __shfl_xor(l1, 32, 64);
    float p0 = pma, p1 = pmb;
    p0 = fmaxf(p0, __shfl_xor(p0, 16, 64)); p0 = fmaxf(p0, __shfl_xor(p0, 32, 64));
    p1 = fmaxf(p1, __shfl_xor(p1, 16, 64)); p1 = fmaxf(p1, __shfl_xor(p1, 32, 64));
    const float invla = 1.0f / l0;
    const float invlb = 1.0f / l1;

    if (lane < 16) {
        conf_s[wv * 16 + mq]      = p0 * invla;
        conf_s[64 + wv * 16 + mq] = p1 * invlb;
    }
    __syncthreads();
    if (tid < 64) {
        float v = conf_s[tid] + conf_s[64 + tid];
        #pragma unroll
        for (int off = 1; off <= 32; off <<= 1) v += __shfl_xor(v, off, 64);
        if (tid == 0) atomicAdd(&g_conf[b], v);
    }

    // ---- epilogue per strip ----
    #pragma unroll
    for (int s = 0; s < 2; ++s) {
        const float invl = s ? invlb : invla;
        float sc[4];
        #pragma unroll
        for (int r = 0; r < 4; ++r)
            sc[r] = keep * __int_as_float(
                __builtin_amdgcn_ds_bpermute((q * 4 + r) << 2, __float_as_int(invl)));
        #pragma unroll
        for (int ctv = 0; ctv < 4; ++ctv)
            #pragma unroll
            for (int r = 0; r < 4; ++r) {
                const f32x4 o = s ? ob[ctv] : oa[ctv];
                g_ao[((size_t)(b * NN + n0 + s * 64 + wv * 16 + q * 4 + r)) * CC + h * DD + ctv * 16 + mq] =
                    f2b(o[r] * sc[r]);
            }
    }
}

// ---------------- Projection: coalesced B (packed) + LDS-staged A ----------
// grid = 1024 blocks of 32 rows; wave = (strip, column-half). 4 blocks/CU.
__global__ __launch_bounds__(256, 4) void proj_kernel(
    const float* __restrict__ pb,
    const float* __restrict__ rp,
    const float* __restrict__ x,
    float* __restrict__ out,
    float* __restrict__ out_c)
{
    const int tid   = threadIdx.x;
    const int wv    = tid >> 6;
    const int lane  = tid & 63;
    const int q     = lane >> 4;
    const int mq    = lane & 15;
    const int strip = wv >> 1;
    const int half  = wv & 1;
    const int base  = blockIdx.x * 32;
    const int r0    = base + strip * 16;

    if (blockIdx.x == 0 && tid < BB)
        out_c[tid] = g_conf[tid] * (1.0f / (float)(HH * NN));   // attn complete

    const float wres = 1.0f / (1.0f + __expf(-rp[0]));

    // ---- stage g_ao slab (32 rows x 192 bf16, contiguous) -> LDS [32][200]
    __shared__ __align__(16) unsigned short xa[32 * 200];   // 12.8 KB
    const unsigned short* aob = g_ao + (size_t)base * CC;
    #pragma unroll
    for (int c = 0; c < 3; ++c) {
        const int f   = c * 256 + tid;          // 16B-unit idx, 768 total
        const int row = f / 24;
        const int k8  = (f - row * 24) * 8;
        *(bf16x8*)(&xa[row * 200 + k8]) = *(const bf16x8*)(aob + (size_t)f * 8);
    }
    __syncthreads();

    bf16x8 af[6];
    #pragma unroll
    for (int kh = 0; kh < 6; ++kh)
        af[kh] = *(const bf16x8*)(&xa[(strip * 16 + mq) * 200 + kh * 32 + q * 8]);

    const int tbase = half * 6;
    bf16x8 bcur[6];
    #pragma unroll
    for (int kh = 0; kh < 6; ++kh)
        bcur[kh] = *(const bf16x8*)(g_pwb + ((size_t)(tbase * 6 + kh) * 64 + lane) * 8);
    #pragma unroll 2
    for (int ot = 0; ot < 6; ++ot) {
        const int o0 = half * 96 + ot * 16;
        bf16x8 bnxt[6];
        if (ot < 5) {
            #pragma unroll
            for (int kh = 0; kh < 6; ++kh)
                bnxt[kh] = *(const bf16x8*)(g_pwb + ((size_t)((tbase + ot + 1) * 6 + kh) * 64 + lane) * 8);
        }
        f32x4 acc = (f32x4){0.f,0.f,0.f,0.f};
        #pragma unroll
        for (int kh = 0; kh < 6; ++kh)
            acc = __builtin_amdgcn_mfma_f32_16x16x32_bf16(af[kh], bcur[kh], acc, 0, 0, 0);
        const float bv = pb[o0 + mq];
        #pragma unroll
        for (int r = 0; r < 4; ++r) {
            const int n = r0 + q * 4 + r;
            const float xv = x[(size_t)n * CC + o0 + mq];
            out[(size_t)n * CC + o0 + mq] = wres * (acc[r] + bv) + (1.0f - wres) * xv;
        }
        #pragma unroll
        for (int kh = 0; kh < 6; ++kh) bcur[kh] = bnxt[kh];
    }
}

extern "C" void kernel_launch(void* const* d_in, const int* in_sizes, int n_in,
                              void* d_out, int out_size, void* d_ws, size_t ws_size,
                              hipStream_t stream)
{
    const float* x  = (const float*)d_in[0];
    const float* qw = (const float*)d_in[1];
    const float* qb = (const float*)d_in[2];
    const float* pw = (const float*)d_in[3];
    const float* pb = (const float*)d_in[4];
    const float* tp = (const float*)d_in[5];
    const float* dl = (const float*)d_in[6];
    const float* rp = (const float*)d_in[7];
    const float* ta = (const float*)d_in[8];

    float* out   = (float*)d_out;
    float* out_c = out + (size_t)BB * NN * CC;

    convert_kernel<<<144, 256, 0, stream>>>(qw, pw);
    qkv_kernel<<<(BB * NN) / 32, 256, 0, stream>>>(x, qb, tp, ta);
    attn_kernel<<<BB * HH * (NN / 128), 256, 0, stream>>>(dl);
    proj_kernel<<<(BB * NN) / 32, 256, 0, stream>>>(pb, rp, x, out, out_c);
}